// Round 15
// baseline (66.698 us; speedup 1.0000x reference)
//
#include <hip/hip_runtime.h>
#include <stdint.h>

namespace {

constexpr int kB = 16;
constexpr int kN = 1024;
constexpr int kF = 128;
constexpr int kHalf = kB * kN * kN;   // 16,777,216 == B*N*N; noise array is [2, B, N, N]
constexpr int kElems = 8;             // elements per thread in the screen kernel
constexpr int kScreenBlocks = kHalf / (256 * kElems);  // 8192

typedef float f32x4 __attribute__((ext_vector_type(4)));  // native vec for nontemporal

__device__ __forceinline__ uint32_t rotl32(uint32_t x, int r) {
  // v_alignbit_b32 x,x,(32-r) == rotr(x,32-r) == rotl(x,r): single instruction.
  return __builtin_amdgcn_alignbit(x, x, 32 - r);
}

// JAX threefry2x32 with key = (0, 42)  [jax.random.key(42)]
__device__ __forceinline__ void tf2x32(uint32_t x0, uint32_t x1,
                                       uint32_t& o0, uint32_t& o1) {
  constexpr uint32_t ks0 = 0u;
  constexpr uint32_t ks1 = 42u;
  constexpr uint32_t ks2 = 0u ^ 42u ^ 0x1BD11BDAu;
  x0 += ks0; x1 += ks1;
#define TFR(r) { x0 += x1; x1 = rotl32(x1, (r)); x1 ^= x0; }
  TFR(13) TFR(15) TFR(26) TFR(6)
  x0 += ks1; x1 += ks2 + 1u;
  TFR(17) TFR(29) TFR(16) TFR(24)
  x0 += ks2; x1 += ks0 + 2u;
  TFR(13) TFR(15) TFR(26) TFR(6)
  x0 += ks0; x1 += ks1 + 3u;
  TFR(17) TFR(29) TFR(16) TFR(24)
  x0 += ks1; x1 += ks2 + 4u;
  TFR(13) TFR(15) TFR(26) TFR(6)
  x0 += ks2; x1 += ks0 + 5u;
#undef TFR
  o0 = x0; o1 = x1;
}

// partitionable mode: bits[idx] = o0 ^ o1 of threefry(key, (idx>>32, idx&0xffffffff))
__device__ __forceinline__ uint32_t random_bits_part(uint32_t idx) {
  uint32_t o0, o1;
  tf2x32(0u, idx, o0, o1);
  return o0 ^ o1;
}

// jax.random.uniform conversion: f in [0,1) from top-23 mantissa bits;
// u = max(1e-10f, f + 1e-10f)   ((maxval-minval) rounds to exactly 1.0f)
__device__ __forceinline__ float bits_to_uniform(uint32_t bits) {
  float f = __uint_as_float((bits >> 9) | 0x3F800000u) - 1.0f;
  return fmaxf(1e-10f, f + 1e-10f);
}

// Full decision for one element (R7-validated: passed absmax 0.0):
// fast v_log path with OCML-exact fallback in the |D|<=0.01 ambiguity band.
__device__ __forceinline__ float decide_elem(uint32_t q, float c0, float c1) {
  const float u0 = bits_to_uniform(random_bits_part(q));
  const float u1 = bits_to_uniform(random_bits_part(q + (uint32_t)kHalf));
  const float lf0 = __log2f(u0);
  const float lf1 = __log2f(u1);
  const float D = c0 * lf1 - c1 * lf0;   // > 0 -> class 1
  float r = (D > 0.0f) ? 1.0f : 0.0f;
  if (fabsf(D) <= 0.01f) {
    const float L0 = -logf(u0);          // OCML, faithful
    const float L1 = -logf(u1);
    r = (c1 * L0 > c0 * L1) ? 1.0f : 0.0f;
  }
  return r;
}

// ---------------------------------------------------------------------------
// Kernel A (runs FIRST, independent of the MLP): fused screen+resolve.
// Treats every element as w = weights[q]; the selected column (i<nn, j==nn)
// gets fixed up afterwards: its out_w slot is overwritten by the MLP's store
// (guarded to i<nn), its out_adj by the patch kernel.
//
// Hot path: ONE threefry hash (u1 only) + ONE raw-bits integer compare.
// Soundness of the w==0 certain-class0 screen (vs the R6 exact chain AND XLA):
//   w==0 -> c1 = 0.001f, c0 = 0.999f exactly.
//   bits <= (8190000<<9)|511  <==>  mant = bits>>9 <= 8190000
//   ==>  u1 <= 8190001/2^23 = 0.9763242  ==>  L1 >= 0.0239609
//   ==>  c0*L1 >= 0.0239369 > 0.0230259 = c1 * (-log(1e-10)) >= c1*L0.
//   Margin 9.1e-4 (~3.8% rel) vs float-eval jitter <= ~1e-6  ==> class0
//   guaranteed (strict-> comparison; ties -> class0 on all paths).
// Survivors (w != 0 or bits > threshold, ~2.3%) are compacted to LDS via
// ballot-aggregated push (ONE ds-atomic per wave per ee, not per lane) and
// resolved densely post-barrier with the R7-validated decide_elem; class-1
// survivors patch out_adj[q]=1.0 (zeros landed pre-barrier; __syncthreads
// drains vmcnt(0)). Worst case 2048 survivors/block == LDS capacity.
// ---------------------------------------------------------------------------
__global__ __launch_bounds__(256) void edge_screen_kernel(
    const float* __restrict__ weights,
    float* __restrict__ out_adj, float* __restrict__ out_w) {
  __shared__ uint32_t s_cnt;
  __shared__ uint32_t s_q[256 * kElems];
  if (threadIdx.x == 0) s_cnt = 0;
  __syncthreads();

  const int tid = blockIdx.x * 256 + threadIdx.x;
  const int q0 = tid * kElems;            // grid sized exactly: q0 < kHalf

  const float4 wqa = *reinterpret_cast<const float4*>(weights + q0);
  const float4 wqb = *reinterpret_cast<const float4*>(weights + q0 + 4);
  float wvals[kElems] = {wqa.x, wqa.y, wqa.z, wqa.w, wqb.x, wqb.y, wqb.z, wqb.w};

  constexpr uint32_t kBitsThr = (8190000u << 9) | 511u;  // see soundness proof

#pragma unroll
  for (int ee = 0; ee < kElems; ++ee) {
    const uint32_t bits =
        random_bits_part((uint32_t)(q0 + ee) + (uint32_t)kHalf);
    const bool surv = (wvals[ee] != 0.0f) || (bits > kBitsThr);
    const uint64_t m = __ballot(surv);
    if (m != 0ull) {                       // wave-uniform branch
      uint32_t base = 0;
      if ((threadIdx.x & 63) == 0)
        base = atomicAdd(&s_cnt, (uint32_t)__popcll(m));
      base = __builtin_amdgcn_readfirstlane(base);
      if (surv) {
        const uint32_t off = __builtin_amdgcn_mbcnt_hi(
            (uint32_t)(m >> 32), __builtin_amdgcn_mbcnt_lo((uint32_t)m, 0u));
        s_q[base + off] = (uint32_t)(q0 + ee);
      }
    }
  }

  const float4 z4 = make_float4(0.0f, 0.0f, 0.0f, 0.0f);
  *reinterpret_cast<float4*>(out_adj + q0) = z4;
  *reinterpret_cast<float4*>(out_adj + q0 + 4) = z4;
  {
    f32x4 v0 = {wvals[0], wvals[1], wvals[2], wvals[3]};
    f32x4 v1 = {wvals[4], wvals[5], wvals[6], wvals[7]};
    __builtin_nontemporal_store(v0, reinterpret_cast<f32x4*>(out_w + q0));
    __builtin_nontemporal_store(v1, reinterpret_cast<f32x4*>(out_w + q0 + 4));
  }

  __syncthreads();   // drains the stores above; publishes s_cnt/s_q

  const uint32_t n = s_cnt;
  for (uint32_t k = threadIdx.x; k < n; k += 256) {
    const uint32_t q = s_q[k];
    const float w = weights[q];            // L2-resident re-read
    const float c1 = fminf(fmaxf(w, 0.001f), 0.999f);
    const float c0 = fminf(fmaxf(1.0f - w, 0.001f), 0.999f);
    if (decide_elem(q, c0, c1) > 0.5f) out_adj[q] = 1.0f;
  }
}

// ---------------------------------------------------------------------------
// Kernel B: probs[b,i] = clip(sigmoid(leaky_relu([left_b, nodes_bi] @ W1 + b1) @ W2 + b2))
// Tiled f32 GEMM: 512 blocks x 256 threads, each block does 32 rows (one b).
// Writes probs into out_w[(b*N + i)*N + nn_b] ONLY for rows i < nn (rows
// i >= nn must keep the screen's weights value -- R14 bug). This store IS the
// final w for those positions. Chunks entirely >= nn early-exit (uniform).
// ---------------------------------------------------------------------------
__global__ __launch_bounds__(256) void mlp_probs_kernel(
    const float* __restrict__ nodes, const int* __restrict__ num_nodes,
    const float* __restrict__ W1, const float* __restrict__ b1,
    const float* __restrict__ W2, const float* __restrict__ b2,
    float* __restrict__ out_w) {
  __shared__ float xs[32][256];   // 32 KiB: per-row input [left(128) | nodes_row(128)]
  __shared__ float bt[16][128];   // 8 KiB: W1 K-tile
  __shared__ float hs[32][128];   // 16 KiB: hidden activations
  __shared__ float h2[32][8];     // 1 KiB: second-layer partials

  const int blk = blockIdx.x;      // 512 blocks = 16 b * 32 row-chunks
  const int b = blk >> 5;
  const int i0 = (blk & 31) * 32;
  const int t = threadIdx.x;
  const int nn = num_nodes[b];
  if (i0 >= nn) return;            // uniform: no row in this chunk has i < nn
  const float* nb = nodes + (size_t)b * kN * kF;
  const float* leftp = nb + (size_t)nn * kF;

  // stage X tile [32 rows][256]
  for (int chunk = 0; chunk < 16; ++chunk) {
    int idx = chunk * 256 + t;   // 0..4095
    int r = idx >> 7;            // 0..31
    int c = idx & 127;
    xs[r][c] = leftp[c];
    xs[r][128 + c] = nb[(size_t)(i0 + r) * kF + c];
  }

  const int tx = t & 31;   // 4 cols each -> 128 cols
  const int ty = t >> 5;   // 4 rows each -> 32 rows
  float acc[4][4];
#pragma unroll
  for (int rr = 0; rr < 4; ++rr)
#pragma unroll
    for (int cc = 0; cc < 4; ++cc) acc[rr][cc] = 0.0f;

  for (int k0 = 0; k0 < 256; k0 += 16) {
    __syncthreads();  // xs ready (first iter) / bt consumers done (later iters)
#pragma unroll
    for (int qq = 0; qq < 8; ++qq) {
      int idx = qq * 256 + t;    // 0..2047
      int kk = idx >> 7;         // 0..15
      int c = idx & 127;
      bt[kk][c] = W1[(size_t)(k0 + kk) * kF + c];
    }
    __syncthreads();
#pragma unroll
    for (int kk = 0; kk < 16; ++kk) {
      float bv0 = bt[kk][4 * tx + 0];
      float bv1 = bt[kk][4 * tx + 1];
      float bv2 = bt[kk][4 * tx + 2];
      float bv3 = bt[kk][4 * tx + 3];
#pragma unroll
      for (int rr = 0; rr < 4; ++rr) {
        float xv = xs[4 * ty + rr][k0 + kk];
        acc[rr][0] = fmaf(xv, bv0, acc[rr][0]);
        acc[rr][1] = fmaf(xv, bv1, acc[rr][1]);
        acc[rr][2] = fmaf(xv, bv2, acc[rr][2]);
        acc[rr][3] = fmaf(xv, bv3, acc[rr][3]);
      }
    }
  }

  // bias + leaky_relu(0.01) -> hs
#pragma unroll
  for (int rr = 0; rr < 4; ++rr)
#pragma unroll
    for (int cc = 0; cc < 4; ++cc) {
      float v = acc[rr][cc] + b1[4 * tx + cc];
      hs[4 * ty + rr][4 * tx + cc] = (v >= 0.0f) ? v : 0.01f * v;
    }
  __syncthreads();

  // second layer: z = hs @ W2 + b2 ; 8 partial sums of 16 per row
  {
    const int r = t >> 3;  // 0..31
    const int q = t & 7;   // 0..7
    float s = 0.0f;
#pragma unroll
    for (int j = 0; j < 16; ++j) {
      int k = q * 16 + j;
      s = fmaf(hs[r][k], W2[k], s);
    }
    h2[r][q] = s;
  }
  __syncthreads();

  if (t < 32 && (i0 + t) < nn) {   // guard: only rows i < nn get probs
    float z = 0.0f;
#pragma unroll
    for (int q = 0; q < 8; ++q) z += h2[t][q];
    z += b2[0];
    double p = 1.0 / (1.0 + exp(-(double)z));  // high-accuracy sigmoid
    float pc = fminf(fmaxf((float)p, 0.001f), 0.999f);
    out_w[(size_t)((b << 10) + i0 + t) * kN + nn] = pc;  // final w for (b,i,nn)
  }
}

// ---------------------------------------------------------------------------
// Kernel C: patch the selected column. For each b, rows i < nn: the final
// w is out_w[(b*N+i)*N+nn] (just written by the MLP); recompute the gumbel
// decision with the R7-validated path and overwrite out_adj.
// ---------------------------------------------------------------------------
__global__ __launch_bounds__(256) void edge_patch_kernel(
    const int* __restrict__ num_nodes,
    float* __restrict__ out_adj, const float* __restrict__ out_w) {
  const int b = blockIdx.x;
  const int nn = num_nodes[b];
  for (int i = threadIdx.x; i < nn; i += 256) {
    const uint32_t q = (uint32_t)((b << 20) + (i << 10) + nn);
    const float p = out_w[q];               // clipped probs from the MLP
    const float c1 = fminf(fmaxf(p, 0.001f), 0.999f);
    const float c0 = fminf(fmaxf(1.0f - p, 0.001f), 0.999f);
    out_adj[q] = decide_elem(q, c0, c1);
  }
}

}  // namespace

extern "C" void kernel_launch(void* const* d_in, const int* in_sizes, int n_in,
                              void* d_out, int out_size, void* d_ws, size_t ws_size,
                              hipStream_t stream) {
  (void)in_sizes; (void)n_in; (void)out_size; (void)d_ws; (void)ws_size;
  const float* nodes = (const float*)d_in[0];
  // d_in[1] = adj (unused by reference)
  const float* weights = (const float*)d_in[2];
  const int* num_nodes = (const int*)d_in[3];
  // d_in[4] = B scalar (compile-time constant here)
  const float* W1 = (const float*)d_in[5];
  const float* b1 = (const float*)d_in[6];
  const float* W2 = (const float*)d_in[7];
  const float* b2 = (const float*)d_in[8];

  float* out_adj = (float*)d_out;
  float* out_w = out_adj + (size_t)kHalf;

  hipLaunchKernelGGL(edge_screen_kernel, dim3(kScreenBlocks), dim3(256), 0, stream,
                     weights, out_adj, out_w);
  hipLaunchKernelGGL(mlp_probs_kernel, dim3(512), dim3(256), 0, stream,
                     nodes, num_nodes, W1, b1, W2, b2, out_w);
  hipLaunchKernelGGL(edge_patch_kernel, dim3(kB), dim3(256), 0, stream,
                     num_nodes, out_adj, out_w);
}

// Round 17
// 59.993 us; speedup vs baseline: 1.1118x; 1.1118x over previous
//
#include <hip/hip_runtime.h>
#include <stdint.h>

namespace {

constexpr int kB = 16;
constexpr int kN = 1024;
constexpr int kF = 128;
constexpr int kHalf = kB * kN * kN;   // 16,777,216 == B*N*N; noise array is [2, B, N, N]
constexpr int kElems = 8;             // elements per thread in the screen kernel
constexpr int kScreenBlocks = kHalf / (256 * kElems);  // 8192

typedef float f32x4 __attribute__((ext_vector_type(4)));  // native vec for nontemporal

__device__ __forceinline__ uint32_t rotl32(uint32_t x, int r) {
  // v_alignbit_b32 x,x,(32-r) == rotr(x,32-r) == rotl(x,r): single instruction.
  return __builtin_amdgcn_alignbit(x, x, 32 - r);
}

// JAX threefry2x32 with key = (0, 42)  [jax.random.key(42)]
__device__ __forceinline__ void tf2x32(uint32_t x0, uint32_t x1,
                                       uint32_t& o0, uint32_t& o1) {
  constexpr uint32_t ks0 = 0u;
  constexpr uint32_t ks1 = 42u;
  constexpr uint32_t ks2 = 0u ^ 42u ^ 0x1BD11BDAu;
  x0 += ks0; x1 += ks1;
#define TFR(r) { x0 += x1; x1 = rotl32(x1, (r)); x1 ^= x0; }
  TFR(13) TFR(15) TFR(26) TFR(6)
  x0 += ks1; x1 += ks2 + 1u;
  TFR(17) TFR(29) TFR(16) TFR(24)
  x0 += ks2; x1 += ks0 + 2u;
  TFR(13) TFR(15) TFR(26) TFR(6)
  x0 += ks0; x1 += ks1 + 3u;
  TFR(17) TFR(29) TFR(16) TFR(24)
  x0 += ks1; x1 += ks2 + 4u;
  TFR(13) TFR(15) TFR(26) TFR(6)
  x0 += ks2; x1 += ks0 + 5u;
#undef TFR
  o0 = x0; o1 = x1;
}

// partitionable mode: bits[idx] = o0 ^ o1 of threefry(key, (idx>>32, idx&0xffffffff))
__device__ __forceinline__ uint32_t random_bits_part(uint32_t idx) {
  uint32_t o0, o1;
  tf2x32(0u, idx, o0, o1);
  return o0 ^ o1;
}

// jax.random.uniform conversion: f in [0,1) from top-23 mantissa bits;
// u = max(1e-10f, f + 1e-10f)   ((maxval-minval) rounds to exactly 1.0f)
__device__ __forceinline__ float bits_to_uniform(uint32_t bits) {
  float f = __uint_as_float((bits >> 9) | 0x3F800000u) - 1.0f;
  return fmaxf(1e-10f, f + 1e-10f);
}

// Full decision for one element (R7-validated: passed absmax 0.0):
// fast v_log path with OCML-exact fallback in the |D|<=0.01 ambiguity band.
__device__ __forceinline__ float decide_elem(uint32_t q, float c0, float c1) {
  const float u0 = bits_to_uniform(random_bits_part(q));
  const float u1 = bits_to_uniform(random_bits_part(q + (uint32_t)kHalf));
  const float lf0 = __log2f(u0);
  const float lf1 = __log2f(u1);
  const float D = c0 * lf1 - c1 * lf0;   // > 0 -> class 1
  float r = (D > 0.0f) ? 1.0f : 0.0f;
  if (fabsf(D) <= 0.01f) {
    const float L0 = -logf(u0);          // OCML, faithful
    const float L1 = -logf(u1);
    r = (c1 * L0 > c0 * L1) ? 1.0f : 0.0f;
  }
  return r;
}

// ---------------------------------------------------------------------------
// Kernel 1: probs[b,i] = clip(sigmoid(leaky_relu([left_b, nodes_bi] @ W1 + b1) @ W2 + b2))
// Tiled f32 GEMM: 512 blocks x 256 threads, each block does 32 rows (one b).
// Result scattered into out_w[(b*N + i)*N + nn_b] (read-before-write staging).
// Blocks whose 32 rows are all >= num_nodes[b] early-exit (uniform); the
// screen kernel overwrites their staging slots with weights anyway.
// ---------------------------------------------------------------------------
__global__ __launch_bounds__(256) void mlp_probs_kernel(
    const float* __restrict__ nodes, const int* __restrict__ num_nodes,
    const float* __restrict__ W1, const float* __restrict__ b1,
    const float* __restrict__ W2, const float* __restrict__ b2,
    float* __restrict__ out_w) {
  __shared__ float xs[32][256];   // 32 KiB: per-row input [left(128) | nodes_row(128)]
  __shared__ float bt[16][128];   // 8 KiB: W1 K-tile
  __shared__ float hs[32][128];   // 16 KiB: hidden activations
  __shared__ float h2[32][8];     // 1 KiB: second-layer partials

  const int blk = blockIdx.x;      // 512 blocks = 16 b * 32 row-chunks
  const int b = blk >> 5;
  const int i0 = (blk & 31) * 32;
  const int t = threadIdx.x;
  const int nn = num_nodes[b];
  if (i0 >= nn) return;            // uniform: no row in this chunk has i < nn
  const float* nb = nodes + (size_t)b * kN * kF;
  const float* leftp = nb + (size_t)nn * kF;

  // stage X tile [32 rows][256]
  for (int chunk = 0; chunk < 16; ++chunk) {
    int idx = chunk * 256 + t;   // 0..4095
    int r = idx >> 7;            // 0..31
    int c = idx & 127;
    xs[r][c] = leftp[c];
    xs[r][128 + c] = nb[(size_t)(i0 + r) * kF + c];
  }

  const int tx = t & 31;   // 4 cols each -> 128 cols
  const int ty = t >> 5;   // 4 rows each -> 32 rows
  float acc[4][4];
#pragma unroll
  for (int rr = 0; rr < 4; ++rr)
#pragma unroll
    for (int cc = 0; cc < 4; ++cc) acc[rr][cc] = 0.0f;

  for (int k0 = 0; k0 < 256; k0 += 16) {
    __syncthreads();  // xs ready (first iter) / bt consumers done (later iters)
#pragma unroll
    for (int qq = 0; qq < 8; ++qq) {
      int idx = qq * 256 + t;    // 0..2047
      int kk = idx >> 7;         // 0..15
      int c = idx & 127;
      bt[kk][c] = W1[(size_t)(k0 + kk) * kF + c];
    }
    __syncthreads();
#pragma unroll
    for (int kk = 0; kk < 16; ++kk) {
      float bv0 = bt[kk][4 * tx + 0];
      float bv1 = bt[kk][4 * tx + 1];
      float bv2 = bt[kk][4 * tx + 2];
      float bv3 = bt[kk][4 * tx + 3];
#pragma unroll
      for (int rr = 0; rr < 4; ++rr) {
        float xv = xs[4 * ty + rr][k0 + kk];
        acc[rr][0] = fmaf(xv, bv0, acc[rr][0]);
        acc[rr][1] = fmaf(xv, bv1, acc[rr][1]);
        acc[rr][2] = fmaf(xv, bv2, acc[rr][2]);
        acc[rr][3] = fmaf(xv, bv3, acc[rr][3]);
      }
    }
  }

  // bias + leaky_relu(0.01) -> hs
#pragma unroll
  for (int rr = 0; rr < 4; ++rr)
#pragma unroll
    for (int cc = 0; cc < 4; ++cc) {
      float v = acc[rr][cc] + b1[4 * tx + cc];
      hs[4 * ty + rr][4 * tx + cc] = (v >= 0.0f) ? v : 0.01f * v;
    }
  __syncthreads();

  // second layer: z = hs @ W2 + b2 ; 8 partial sums of 16 per row
  {
    const int r = t >> 3;  // 0..31
    const int q = t & 7;   // 0..7
    float s = 0.0f;
#pragma unroll
    for (int j = 0; j < 16; ++j) {
      int k = q * 16 + j;
      s = fmaf(hs[r][k], W2[k], s);
    }
    h2[r][q] = s;
  }
  __syncthreads();

  if (t < 32) {
    float z = 0.0f;
#pragma unroll
    for (int q = 0; q < 8; ++q) z += h2[t][q];
    z += b2[0];
    double p = 1.0 / (1.0 + exp(-(double)z));  // high-accuracy sigmoid
    float pc = fminf(fmaxf((float)p, 0.001f), 0.999f);
    // stage into out_w at [b][i][nn]; screen kernel's owning thread reads it back
    out_w[(size_t)((b << 10) + i0 + t) * kN + nn] = pc;
  }
}

// ---------------------------------------------------------------------------
// Kernel 2 (fused screen+resolve): per (b,i,j), 8 elements per thread.
// R13 structure (fastest so far) with stores HOISTED above the hash loop so
// the write stream drains under the ~600-op hash phase, and nontemporal on
// BOTH output streams (neither is re-read except rare survivor patches;
// keeps L2 for the weights fetch stream).
//
// Hot path: ONE threefry hash (u1 only) + ONE raw-bits integer compare.
// Soundness of the w==0 certain-class0 screen (vs the R6 exact chain AND XLA):
//   w==0 -> c1 = 0.001f, c0 = 0.999f exactly.
//   bits <= (8190000<<9)|511  <==>  mant = bits>>9 <= 8190000
//   ==>  u1 <= 8190001/2^23 = 0.9763242  ==>  L1 >= 0.0239609
//   ==>  c0*L1 >= 0.0239369 > 0.0230259 = c1 * (-log(1e-10)) >= c1*L0.
//   Margin 9.1e-4 (~3.8% rel) vs float-eval jitter <= ~1e-6  ==> class0
//   guaranteed (strict-> comparison; ties -> class0 on all paths).
// Survivors (w != 0, i.e. the selected column, or bits > threshold; ~2.3%)
// are compacted to LDS via per-lane atomic push (exec-masked divergent body
// -- measured cheaper than ballot aggregation, R15) and resolved densely
// post-barrier with the R7-validated decide_elem. Class-1 survivors patch
// out_adj[q]=1.0 (zero-stores landed pre-barrier; __syncthreads drains
// vmcnt(0), so the patch is ordered after them). Worst case 2048
// survivors/block == LDS capacity -- cannot overflow.
// ---------------------------------------------------------------------------
__global__ __launch_bounds__(256) void edge_screen_kernel(
    const float* __restrict__ weights, const int* __restrict__ num_nodes,
    float* __restrict__ out_adj, float* __restrict__ out_w) {
  __shared__ uint32_t s_cnt;
  __shared__ uint32_t s_q[256 * kElems];
  __shared__ float s_w[256 * kElems];
  if (threadIdx.x == 0) s_cnt = 0;
  __syncthreads();

  const int tid = blockIdx.x * 256 + threadIdx.x;
  const int q0 = tid * kElems;            // grid sized exactly: q0 < kHalf
  const int b = q0 >> 20;                 // N*N = 2^20
  const int i = (q0 >> 10) & 1023;
  const int j0 = q0 & 1023;               // kElems | 1024: all 8 in one row
  const int nn = num_nodes[b];
  const bool rowsel = (i < nn);
  const int rowbase = q0 - j0;            // (b*N + i)*N

  // p staged by kernel 1 at out_w[rowbase + nn]; only the thread whose span
  // contains column nn needs it (it reads before it overwrites - same thread).
  float pv = 0.0f;
  if (rowsel && nn >= j0 && nn < j0 + kElems) pv = out_w[rowbase + nn];

  const float4 wqa = *reinterpret_cast<const float4*>(weights + q0);
  const float4 wqb = *reinterpret_cast<const float4*>(weights + q0 + 4);
  float wvals[kElems] = {wqa.x, wqa.y, wqa.z, wqa.w, wqb.x, wqb.y, wqb.z, wqb.w};

  // final w per element (pv at the selected column) -- no hash dependency
  float ow[kElems];
#pragma unroll
  for (int ee = 0; ee < kElems; ++ee) {
    const int j = j0 + ee;
    ow[ee] = (rowsel && (j == nn)) ? pv : wvals[ee];
  }

  // ---- stores FIRST: drain the write stream under the hash phase ----
  {
    f32x4 z4 = {0.0f, 0.0f, 0.0f, 0.0f};
    __builtin_nontemporal_store(z4, reinterpret_cast<f32x4*>(out_adj + q0));
    __builtin_nontemporal_store(z4, reinterpret_cast<f32x4*>(out_adj + q0 + 4));
    f32x4 v0 = {ow[0], ow[1], ow[2], ow[3]};
    f32x4 v1 = {ow[4], ow[5], ow[6], ow[7]};
    __builtin_nontemporal_store(v0, reinterpret_cast<f32x4*>(out_w + q0));
    __builtin_nontemporal_store(v1, reinterpret_cast<f32x4*>(out_w + q0 + 4));
  }

  constexpr uint32_t kBitsThr = (8190000u << 9) | 511u;  // see soundness proof

#pragma unroll
  for (int ee = 0; ee < kElems; ++ee) {
    const uint32_t bits =
        random_bits_part((uint32_t)(q0 + ee) + (uint32_t)kHalf);
    if ((ow[ee] != 0.0f) || (bits > kBitsThr)) {
      uint32_t k = atomicAdd(&s_cnt, 1u);
      s_q[k] = (uint32_t)(q0 + ee);
      s_w[k] = ow[ee];
    }
  }

  __syncthreads();   // drains the stores above; publishes s_cnt/s_q/s_w

  const uint32_t n = s_cnt;
  for (uint32_t k = threadIdx.x; k < n; k += 256) {
    const uint32_t q = s_q[k];
    const float w = s_w[k];
    const float c1 = fminf(fmaxf(w, 0.001f), 0.999f);
    const float c0 = fminf(fmaxf(1.0f - w, 0.001f), 0.999f);
    if (decide_elem(q, c0, c1) > 0.5f) out_adj[q] = 1.0f;
  }
}

}  // namespace

extern "C" void kernel_launch(void* const* d_in, const int* in_sizes, int n_in,
                              void* d_out, int out_size, void* d_ws, size_t ws_size,
                              hipStream_t stream) {
  (void)in_sizes; (void)n_in; (void)out_size; (void)d_ws; (void)ws_size;
  const float* nodes = (const float*)d_in[0];
  // d_in[1] = adj (unused by reference)
  const float* weights = (const float*)d_in[2];
  const int* num_nodes = (const int*)d_in[3];
  // d_in[4] = B scalar (compile-time constant here)
  const float* W1 = (const float*)d_in[5];
  const float* b1 = (const float*)d_in[6];
  const float* W2 = (const float*)d_in[7];
  const float* b2 = (const float*)d_in[8];

  float* out_adj = (float*)d_out;
  float* out_w = out_adj + (size_t)kHalf;

  hipLaunchKernelGGL(mlp_probs_kernel, dim3(512), dim3(256), 0, stream,
                     nodes, num_nodes, W1, b1, W2, b2, out_w);
  hipLaunchKernelGGL(edge_screen_kernel, dim3(kScreenBlocks), dim3(256), 0, stream,
                     weights, num_nodes, out_adj, out_w);
}